// Round 8
// baseline (224.719 us; speedup 1.0000x reference)
//
#include <hip/hip_runtime.h>
#include <hip/hip_bf16.h>

typedef __attribute__((ext_vector_type(8))) short short8;
typedef __attribute__((ext_vector_type(4))) float f32x4;

#define NNODES 50000

__device__ __forceinline__ float b2f(unsigned short s) {
  union { unsigned int u; float f; } c; c.u = ((unsigned int)s) << 16;
  return c.f;
}
__device__ __forceinline__ unsigned short f2b(float f) {
  return __bfloat16_as_ushort(__float2bfloat16(f));  // RNE
}
__device__ __forceinline__ unsigned int pkcvt(float a, float b) {
  return (unsigned int)f2b(a) | ((unsigned int)f2b(b) << 16);
}

// global_load_lds, 16B per lane: per-lane GLOBAL src addr, wave-uniform LDS
// base; HW writes LDS at base + lane*16 (m104 semantics).
__device__ __forceinline__ void gl_lds16(const void* g, void* l) {
  __builtin_amdgcn_global_load_lds((const __attribute__((address_space(1))) unsigned int*)g,
                                   (__attribute__((address_space(3))) unsigned int*)l, 16, 0, 0);
}

// ---------------- degree histogram (+rank capture) + W transpose/bf16 ----------------
// The atomicAdd return value IS the edge's within-dst rank; persisting it
// (3.2MB streaming write) makes the CSR fill atomic-free (rank trick).
__global__ __launch_bounds__(256) void k_deg(const int* __restrict__ ei, int* __restrict__ deg, int E,
                                             int* __restrict__ rnk,
                                             const float* __restrict__ W1, const float* __restrict__ W2,
                                             unsigned short* __restrict__ w1t, unsigned short* __restrict__ w2t) {
  int idx = blockIdx.x * 256 + threadIdx.x;
  if (idx < E) {
    int r = atomicAdd(&deg[ei[E + idx]], 1);
    rnk[idx] = r;
  }
  if (idx < 256 * 512) { int nn = idx >> 9, kk = idx & 511; w1t[idx] = f2b(W1[kk * 256 + nn]); }
  int i2 = idx - 256 * 512;
  if (i2 >= 0 && i2 < 64 * 256) { int nn = i2 >> 8, kk = i2 & 255; w2t[i2] = f2b(W2[kk * 64 + nn]); }
}

// ---------------- scan phase A ----------------
__global__ __launch_bounds__(256) void k_scanA(const int* __restrict__ deg, int* __restrict__ excl,
                                               int* __restrict__ blksum, float* __restrict__ dinv, int n) {
  const int i = blockIdx.x * 256 + threadIdx.x;
  const int lane = threadIdx.x & 63, wid = threadIdx.x >> 6;
  const int v = (i < n) ? deg[i] : 0;
  int x = v;
#pragma unroll
  for (int o = 1; o < 64; o <<= 1) {
    int y = __shfl_up(x, o, 64);
    if (lane >= o) x += y;
  }
  __shared__ int wsum[4];
  if (lane == 63) wsum[wid] = x;
  __syncthreads();
  int woff = 0;
  for (int w = 0; w < wid; ++w) woff += wsum[w];
  const int incl = x + woff;
  if (i < n) {
    excl[i] = incl - v;
    dinv[i] = rsqrtf((float)v + 1.0f);  // +1 self loop
  }
  if (threadIdx.x == 255) blksum[blockIdx.x] = incl;
}

// ---------------- scan phase C ----------------
__global__ __launch_bounds__(256) void k_scanC(const int* __restrict__ excl, const int* __restrict__ blksum,
                                               int* __restrict__ rowptr, int n, int E) {
  const int t = threadIdx.x;
  int partial = 0;
  for (int j = t; j < (int)blockIdx.x; j += 256) partial += blksum[j];
#pragma unroll
  for (int o = 32; o > 0; o >>= 1) partial += __shfl_xor(partial, o, 64);
  __shared__ int ws[4];
  if ((t & 63) == 0) ws[t >> 6] = partial;
  __syncthreads();
  const int off = ws[0] + ws[1] + ws[2] + ws[3];
  const int i = blockIdx.x * 256 + t;
  if (i < n) rowptr[i] = excl[i] + off;
  if (i == 0) rowptr[n] = E;
}

// ---------------- atomic-free CSR fill + x->bf16 conversion (fused) ----------------
__global__ __launch_bounds__(256) void k_fillx(const int* __restrict__ ei, const int* __restrict__ rowptr,
                                               const int* __restrict__ rnk, int* __restrict__ csr, int E,
                                               const float* __restrict__ x, unsigned short* __restrict__ xb) {
  int idx = blockIdx.x * 256 + threadIdx.x;
  if (idx < E) {
    const int dst = ei[E + idx];
    csr[rowptr[dst] + rnk[idx]] = ei[idx];
  }
  if (idx < (NNODES * 512) / 8) {
    const float4 v0 = *(const float4*)(x + (size_t)idx * 8);
    const float4 v1 = *(const float4*)(x + (size_t)idx * 8 + 4);
    uint4 p;
    p.x = pkcvt(v0.x, v0.y); p.y = pkcvt(v0.z, v0.w);
    p.z = pkcvt(v1.x, v1.y); p.w = pkcvt(v1.z, v1.w);
    *(uint4*)(xb + (size_t)idx * 8) = p;
  }
}

// ---------------- GEMM1: hs1b = bf16(dinv[row] * (xb @ W1)) ----------------
// 128x128 tile (BN 64->128): 16 MFMA per K-step per wave (2x R7's 8) against
// the same per-step sync cost -> work:sync ratio doubled. Depth-2 pipelined
// gl_lds staging, counted vmcnt(4) (4 gl_lds/wave/stage, never drained to 0
// in steady state). Both-sides chunk-XOR swizzle (row offsets are multiples
// of 16, so the (r>>1)&3 algebra is unchanged from R6). LDS 32KB -> ~4
// blocks/CU; grid 784 = 391x2 ~ 3.05/CU all-resident. 2 col-siblings at bid
// stride 8 -> same XCD -> one L2 fill of the A panel serves both.
__global__ __launch_bounds__(256) void k_gemm1(const unsigned short* __restrict__ xb,
    const unsigned short* __restrict__ w1t, const float* __restrict__ dinv,
    unsigned short* __restrict__ hs1b) {
  const int M = NNODES, K = 512, N = 256;
  const int NRB = (NNODES + 127) / 128;  // 391
  const int bid = blockIdx.x;
  const int rowblk = (bid >> 4) * 8 + (bid & 7);
  const int colblk = (bid >> 3) & 1;
  if (rowblk >= NRB) return;

  __shared__ unsigned short Ab[2][128][32];  // 16 KB
  __shared__ unsigned short Bb[2][128][32];  // 16 KB

  const int tid = threadIdx.x;
  const int w = tid >> 6, lane = tid & 63;
  const int sub = lane >> 2;                 // staging row within 16-row window
  const int brow = rowblk * 128, bcol = colblk * 128;
  const int wr = w >> 1, wc = w & 1;         // 2x2 wave grid, 64x64 out each
  const int lr = lane & 15, lk = lane >> 4;

  const int swc = ((lane & 3) ^ ((lane >> 3) & 3)) * 8;   // pre-swizzled src chunk
  const int rch = (lk ^ ((lr >> 1) & 3)) * 8;             // read-side swizzled chunk

  // A staging rows: wave w covers rows w*32 .. w*32+31 (two 16-row windows)
  int gr0 = brow + w * 32 + sub;      if (gr0 >= M) gr0 = M - 1;
  int gr1 = brow + w * 32 + 16 + sub; if (gr1 >= M) gr1 = M - 1;
  const int gb0 = bcol + w * 32 + sub;       // < 256 always
  const int gb1 = bcol + w * 32 + 16 + sub;

  const unsigned short* a0p = xb + (size_t)gr0 * K + swc;
  const unsigned short* a1p = xb + (size_t)gr1 * K + swc;
  const unsigned short* b0p = w1t + (size_t)gb0 * K + swc;
  const unsigned short* b1p = w1t + (size_t)gb1 * K + swc;

  f32x4 acc[4][4] = {};

#define G1_STAGE(BUF, KT) do { \
    gl_lds16(a0p + (KT), &Ab[BUF][w * 32][0]); \
    gl_lds16(a1p + (KT), &Ab[BUF][w * 32 + 16][0]); \
    gl_lds16(b0p + (KT), &Bb[BUF][w * 32][0]); \
    gl_lds16(b1p + (KT), &Bb[BUF][w * 32 + 16][0]); \
  } while (0)

  G1_STAGE(0, 0);
  G1_STAGE(1, 32);
  asm volatile("s_waitcnt vmcnt(4)" ::: "memory");  // stage 0 done; stage 1 in flight
  __builtin_amdgcn_s_barrier();

  for (int s = 0; s < 16; ++s) {
    const int cur = s & 1;
    short8 af[4], bf[4];
#pragma unroll
    for (int m = 0; m < 4; ++m) af[m] = *(const short8*)&Ab[cur][wr * 64 + m * 16 + lr][rch];
#pragma unroll
    for (int n = 0; n < 4; ++n) bf[n] = *(const short8*)&Bb[cur][wc * 64 + n * 16 + lr][rch];
    if (s < 14) {
      asm volatile("s_waitcnt lgkmcnt(0)" ::: "memory");  // frags in regs
      __builtin_amdgcn_s_barrier();                       // all waves done with buf cur
      G1_STAGE(cur, (s + 2) * 32);                        // tile s+2 -> buf cur
    }
#pragma unroll
    for (int m = 0; m < 4; ++m)
#pragma unroll
      for (int n = 0; n < 4; ++n)
        acc[m][n] = __builtin_amdgcn_mfma_f32_16x16x32_bf16(af[m], bf[n], acc[m][n], 0, 0, 0);
    if (s < 14)      asm volatile("s_waitcnt vmcnt(4)" ::: "memory");  // s+1 landed; s+2 in flight
    else if (s == 14) asm volatile("s_waitcnt vmcnt(0)" ::: "memory"); // last stage (tile 15) landed
    if (s < 15) __builtin_amdgcn_s_barrier();
  }
#undef G1_STAGE

#pragma unroll
  for (int m = 0; m < 4; ++m) {
#pragma unroll
    for (int n = 0; n < 4; ++n) {
      const int col = bcol + wc * 64 + n * 16 + lr;
#pragma unroll
      for (int j = 0; j < 4; ++j) {
        const int row = brow + wr * 64 + m * 16 + lk * 4 + j;
        if (row < M) hs1b[(size_t)row * N + col] = f2b(acc[m][n][j] * dinv[row]);
      }
    }
  }
}

// ---------------- FUSED agg1 + relu/bias + GEMM2 + prescale -> hs2b ----------------
// R2's proven 8-deep gather batch. 16 nodes/block, wave gathers 4 nodes;
// phase 2: wave w computes cols w*16..w*16+15 of the 16x64 output.
__global__ __launch_bounds__(256) void k_agg1g(const int* __restrict__ rowptr,
    const int* __restrict__ csr, const unsigned short* __restrict__ hs1b,
    const float* __restrict__ dinv, const float* __restrict__ b1,
    const unsigned short* __restrict__ w2t, unsigned short* __restrict__ hs2b) {
  const int M = NNODES;
  __shared__ unsigned short h1t[16][264];  // 8.4 KB
  const int tid = threadIdx.x;
  const int w = tid >> 6, lane = tid & 63;
  const int lr = lane & 15, lk = lane >> 4;
  const int brow = blockIdx.x * 16;

  const float4 bb = *(const float4*)(b1 + lane * 4);

  // ---- phase 1: each wave aggregates 4 nodes ----
  for (int i = 0; i < 4; ++i) {
    const int ldsrow = w * 4 + i;
    const int d = brow + ldsrow;
    f32x4 acc = {0.f, 0.f, 0.f, 0.f};
    if (d < M) {
      const int a = rowptr[d], bnd = rowptr[d + 1];
      ushort4 sv = *(const ushort4*)(hs1b + (size_t)d * 256 + lane * 4);  // self loop
      acc[0] = b2f(sv.x); acc[1] = b2f(sv.y); acc[2] = b2f(sv.z); acc[3] = b2f(sv.w);
      int e = a;
      for (; e + 8 <= bnd; e += 8) {
        int s[8];
#pragma unroll
        for (int j = 0; j < 8; ++j) s[j] = csr[e + j];
        ushort4 v[8];
#pragma unroll
        for (int j = 0; j < 8; ++j) v[j] = *(const ushort4*)(hs1b + (size_t)s[j] * 256 + lane * 4);
#pragma unroll
        for (int j = 0; j < 8; ++j) {
          acc[0] += b2f(v[j].x); acc[1] += b2f(v[j].y);
          acc[2] += b2f(v[j].z); acc[3] += b2f(v[j].w);
        }
      }
      for (; e + 2 <= bnd; e += 2) {
        int s0 = csr[e], s1 = csr[e + 1];
        ushort4 v0 = *(const ushort4*)(hs1b + (size_t)s0 * 256 + lane * 4);
        ushort4 v1 = *(const ushort4*)(hs1b + (size_t)s1 * 256 + lane * 4);
        acc[0] += b2f(v0.x) + b2f(v1.x); acc[1] += b2f(v0.y) + b2f(v1.y);
        acc[2] += b2f(v0.z) + b2f(v1.z); acc[3] += b2f(v0.w) + b2f(v1.w);
      }
      for (; e < bnd; ++e) {
        int s0 = csr[e];
        ushort4 v0 = *(const ushort4*)(hs1b + (size_t)s0 * 256 + lane * 4);
        acc[0] += b2f(v0.x); acc[1] += b2f(v0.y); acc[2] += b2f(v0.z); acc[3] += b2f(v0.w);
      }
      const float di = dinv[d];
      acc[0] = fmaxf(0.f, acc[0] * di + bb.x);
      acc[1] = fmaxf(0.f, acc[1] * di + bb.y);
      acc[2] = fmaxf(0.f, acc[2] * di + bb.z);
      acc[3] = fmaxf(0.f, acc[3] * di + bb.w);
    }
    uint2 pk;
    pk.x = pkcvt(acc[0], acc[1]);
    pk.y = pkcvt(acc[2], acc[3]);
    *(uint2*)&h1t[ldsrow][lane * 4] = pk;
  }

  __syncthreads();

  // ---- phase 2: 16x64x256 MFMA; wave w -> cols w*16..w*16+15 ----
  f32x4 acc2 = {};
#pragma unroll
  for (int s = 0; s < 8; ++s) {
    short8 af = *(const short8*)&h1t[lr][s * 32 + lk * 8];
    short8 bfv = *(const short8*)(w2t + (size_t)(w * 16 + lr) * 256 + s * 32 + lk * 8);
    acc2 = __builtin_amdgcn_mfma_f32_16x16x32_bf16(af, bfv, acc2, 0, 0, 0);
  }

  {
    const int col = w * 16 + lr;
#pragma unroll
    for (int j = 0; j < 4; ++j) {
      const int row = brow + lk * 4 + j;
      if (row < M) hs2b[(size_t)row * 64 + col] = f2b(acc2[j] * dinv[row]);
    }
  }
}

// ---------------- fused agg2 + bias + log_softmax: wave per dst node ----------------
__global__ __launch_bounds__(256) void k_agg2f(const int* __restrict__ rowptr,
    const int* __restrict__ csr, const unsigned short* __restrict__ hs2b,
    const float* __restrict__ dinv, const float* __restrict__ b2,
    float* __restrict__ out) {
  const int d = blockIdx.x * 4 + (threadIdx.x >> 6);
  if (d >= NNODES) return;
  const int lane = threadIdx.x & 63;
  const int a = rowptr[d], bnd = rowptr[d + 1];

  float acc = b2f(hs2b[(size_t)d * 64 + lane]);

  int i = a;
  for (; i + 16 <= bnd; i += 16) {
    int s[16];
#pragma unroll
    for (int j = 0; j < 16; ++j) s[j] = csr[i + j];
    unsigned short v[16];
#pragma unroll
    for (int j = 0; j < 16; ++j) v[j] = hs2b[(size_t)s[j] * 64 + lane];
#pragma unroll
    for (int j = 0; j < 16; ++j) acc += b2f(v[j]);
  }
  for (; i + 4 <= bnd; i += 4) {
    int s[4];
#pragma unroll
    for (int j = 0; j < 4; ++j) s[j] = csr[i + j];
    unsigned short v[4];
#pragma unroll
    for (int j = 0; j < 4; ++j) v[j] = hs2b[(size_t)s[j] * 64 + lane];
#pragma unroll
    for (int j = 0; j < 4; ++j) acc += b2f(v[j]);
  }
  for (; i < bnd; ++i) acc += b2f(hs2b[(size_t)csr[i] * 64 + lane]);

  float v = acc * dinv[d] + b2[lane];
  float m = v;
#pragma unroll
  for (int o = 32; o > 0; o >>= 1) m = fmaxf(m, __shfl_xor(m, o, 64));
  float ex = expf(v - m);
  float s = ex;
#pragma unroll
  for (int o = 32; o > 0; o >>= 1) s += __shfl_xor(s, o, 64);
  out[(size_t)d * 64 + lane] = v - m - logf(s);
}

extern "C" void kernel_launch(void* const* d_in, const int* in_sizes, int n_in,
                              void* d_out, int out_size, void* d_ws, size_t ws_size,
                              hipStream_t stream) {
  const float* x  = (const float*)d_in[0];
  const int*   ei = (const int*)d_in[1];
  const float* W1 = (const float*)d_in[2];
  const float* b1 = (const float*)d_in[3];
  const float* W2 = (const float*)d_in[4];
  const float* b2 = (const float*)d_in[5];
  float* out = (float*)d_out;
  const int E = in_sizes[1] / 2;
  const int n = NNODES;
  const int nblk = (n + 255) / 256;

  char* ws = (char*)d_ws;
  size_t off = 0;
  auto alloc = [&](size_t bytes) { char* p = ws + off; off = (off + bytes + 255) & ~(size_t)255; return p; };
  int*            deg    = (int*)alloc((size_t)n * 4);
  float*          dinv   = (float*)alloc((size_t)n * 4);
  int*            excl   = (int*)alloc((size_t)n * 4);
  int*            blksum = (int*)alloc((size_t)nblk * 4);
  int*            rowptr = (int*)alloc((size_t)(n + 1) * 4);
  int*            rnk    = (int*)alloc((size_t)E * 4);
  int*            csr    = (int*)alloc((size_t)E * 4);
  unsigned short* w1t    = (unsigned short*)alloc(256 * 512 * 2);
  unsigned short* w2t    = (unsigned short*)alloc(64 * 256 * 2);
  unsigned short* hs1b   = (unsigned short*)alloc((size_t)n * 256 * 2);
  unsigned short* hs2b   = (unsigned short*)alloc((size_t)n * 64 * 2);
  unsigned short* xb     = (unsigned short*)alloc((size_t)n * 512 * 2);  // bf16 copy of x
  (void)ws_size; (void)n_in; (void)out_size;

  hipMemsetAsync(deg, 0, (size_t)n * 4, stream);
  k_deg<<<(E + 255) / 256, 256, 0, stream>>>(ei, deg, E, rnk, W1, W2, w1t, w2t);
  k_scanA<<<nblk, 256, 0, stream>>>(deg, excl, blksum, dinv, n);
  k_scanC<<<nblk, 256, 0, stream>>>(excl, blksum, rowptr, n, E);
  // atomic-free fill (rank trick) + xb conversion fused
  k_fillx<<<(NNODES * 512 / 8 + 255) / 256, 256, 0, stream>>>(ei, rowptr, rnk, csr, E, x, xb);
  // 49 groups x 16 blocks: row = (bid>>4)*8 + (bid&7), col = (bid>>3)&1
  k_gemm1<<<49 * 16, 256, 0, stream>>>(xb, w1t, dinv, hs1b);
  k_agg1g<<<(n + 15) / 16, 256, 0, stream>>>(rowptr, csr, hs1b, dinv, b1, w2t, hs2b);
  k_agg2f<<<(n + 3) / 4, 256, 0, stream>>>(rowptr, csr, hs2b, dinv, b2, out);
}

// Round 9
// 222.430 us; speedup vs baseline: 1.0103x; 1.0103x over previous
//
#include <hip/hip_runtime.h>
#include <hip/hip_bf16.h>

typedef __attribute__((ext_vector_type(8))) short short8;
typedef __attribute__((ext_vector_type(4))) float f32x4;

#define NNODES 50000

__device__ __forceinline__ float b2f(unsigned short s) {
  union { unsigned int u; float f; } c; c.u = ((unsigned int)s) << 16;
  return c.f;
}
__device__ __forceinline__ unsigned short f2b(float f) {
  return __bfloat16_as_ushort(__float2bfloat16(f));  // RNE
}
__device__ __forceinline__ unsigned int pkcvt(float a, float b) {
  return (unsigned int)f2b(a) | ((unsigned int)f2b(b) << 16);
}

// global_load_lds, 16B per lane: per-lane GLOBAL src addr, wave-uniform LDS
// base; HW writes LDS at base + lane*16 (m104 semantics).
__device__ __forceinline__ void gl_lds16(const void* g, void* l) {
  __builtin_amdgcn_global_load_lds((const __attribute__((address_space(1))) unsigned int*)g,
                                   (__attribute__((address_space(3))) unsigned int*)l, 16, 0, 0);
}

// ---------------- degree histogram (+rank capture) + W transpose/bf16 ----------------
// The atomicAdd return value IS the edge's within-dst rank; persisting it
// (3.2MB streaming write) makes the CSR fill atomic-free (rank trick).
__global__ __launch_bounds__(256) void k_deg(const int* __restrict__ ei, int* __restrict__ deg, int E,
                                             int* __restrict__ rnk,
                                             const float* __restrict__ W1, const float* __restrict__ W2,
                                             unsigned short* __restrict__ w1t, unsigned short* __restrict__ w2t) {
  int idx = blockIdx.x * 256 + threadIdx.x;
  if (idx < E) {
    int r = atomicAdd(&deg[ei[E + idx]], 1);
    rnk[idx] = r;
  }
  if (idx < 256 * 512) { int nn = idx >> 9, kk = idx & 511; w1t[idx] = f2b(W1[kk * 256 + nn]); }
  int i2 = idx - 256 * 512;
  if (i2 >= 0 && i2 < 64 * 256) { int nn = i2 >> 8, kk = i2 & 255; w2t[i2] = f2b(W2[kk * 64 + nn]); }
}

// ---------------- scan phase A ----------------
__global__ __launch_bounds__(256) void k_scanA(const int* __restrict__ deg, int* __restrict__ excl,
                                               int* __restrict__ blksum, float* __restrict__ dinv, int n) {
  const int i = blockIdx.x * 256 + threadIdx.x;
  const int lane = threadIdx.x & 63, wid = threadIdx.x >> 6;
  const int v = (i < n) ? deg[i] : 0;
  int x = v;
#pragma unroll
  for (int o = 1; o < 64; o <<= 1) {
    int y = __shfl_up(x, o, 64);
    if (lane >= o) x += y;
  }
  __shared__ int wsum[4];
  if (lane == 63) wsum[wid] = x;
  __syncthreads();
  int woff = 0;
  for (int w = 0; w < wid; ++w) woff += wsum[w];
  const int incl = x + woff;
  if (i < n) {
    excl[i] = incl - v;
    dinv[i] = rsqrtf((float)v + 1.0f);  // +1 self loop
  }
  if (threadIdx.x == 255) blksum[blockIdx.x] = incl;
}

// ---------------- scan phase C ----------------
__global__ __launch_bounds__(256) void k_scanC(const int* __restrict__ excl, const int* __restrict__ blksum,
                                               int* __restrict__ rowptr, int n, int E) {
  const int t = threadIdx.x;
  int partial = 0;
  for (int j = t; j < (int)blockIdx.x; j += 256) partial += blksum[j];
#pragma unroll
  for (int o = 32; o > 0; o >>= 1) partial += __shfl_xor(partial, o, 64);
  __shared__ int ws[4];
  if ((t & 63) == 0) ws[t >> 6] = partial;
  __syncthreads();
  const int off = ws[0] + ws[1] + ws[2] + ws[3];
  const int i = blockIdx.x * 256 + t;
  if (i < n) rowptr[i] = excl[i] + off;
  if (i == 0) rowptr[n] = E;
}

// ---------------- atomic-free CSR fill + x->bf16 conversion (fused) ----------------
__global__ __launch_bounds__(256) void k_fillx(const int* __restrict__ ei, const int* __restrict__ rowptr,
                                               const int* __restrict__ rnk, int* __restrict__ csr, int E,
                                               const float* __restrict__ x, unsigned short* __restrict__ xb) {
  int idx = blockIdx.x * 256 + threadIdx.x;
  if (idx < E) {
    const int dst = ei[E + idx];
    csr[rowptr[dst] + rnk[idx]] = ei[idx];
  }
  if (idx < (NNODES * 512) / 8) {
    const float4 v0 = *(const float4*)(x + (size_t)idx * 8);
    const float4 v1 = *(const float4*)(x + (size_t)idx * 8 + 4);
    uint4 p;
    p.x = pkcvt(v0.x, v0.y); p.y = pkcvt(v0.z, v0.w);
    p.z = pkcvt(v1.x, v1.y); p.w = pkcvt(v1.z, v1.w);
    *(uint4*)(xb + (size_t)idx * 8) = p;
  }
}

// ---------------- GEMM1: hs1b = bf16(dinv[row] * (xb @ W1)) ----------------
// R7 config (128x64, the measured local optimum; 128x128 regressed +6us in
// R8 -- at these small K-panels TLP beats per-wave work amplification).
// Depth-2 pipelined gl_lds staging, counted vmcnt(3), both-sides chunk-XOR
// swizzle. LDS 24KB -> 6 blocks/CU; grid 1568 ~ 6.1/CU all-resident.
__global__ __launch_bounds__(256) void k_gemm1(const unsigned short* __restrict__ xb,
    const unsigned short* __restrict__ w1t, const float* __restrict__ dinv,
    unsigned short* __restrict__ hs1b) {
  const int M = NNODES, K = 512, N = 256;
  const int NRB = (NNODES + 127) / 128;  // 391
  const int bid = blockIdx.x;
  const int rowblk = (bid >> 5) * 8 + (bid & 7);
  const int colblk = (bid >> 3) & 3;
  if (rowblk >= NRB) return;

  __shared__ unsigned short Ab[2][128][32];  // 16 KB
  __shared__ unsigned short Bb[2][64][32];   //  8 KB

  const int tid = threadIdx.x;
  const int w = tid >> 6, lane = tid & 63;
  const int sub = lane >> 2;                 // staging row within wave window
  const int brow = rowblk * 128, bcol = colblk * 64;
  const int wr = w >> 1, wc = w & 1;         // 2x2 wave grid, 64x32 out each
  const int lr = lane & 15, lk = lane >> 4;

  const int swc = ((lane & 3) ^ ((lane >> 3) & 3)) * 8;   // pre-swizzled src chunk
  const int rch = (lk ^ ((lr >> 1) & 3)) * 8;             // read-side swizzled chunk

  int gr0 = brow + w * 16 + sub;      if (gr0 >= M) gr0 = M - 1;
  int gr1 = brow + 64 + w * 16 + sub; if (gr1 >= M) gr1 = M - 1;
  const int grB = bcol + w * 16 + sub;

  const unsigned short* a0p = xb + (size_t)gr0 * K + swc;
  const unsigned short* a1p = xb + (size_t)gr1 * K + swc;
  const unsigned short* bp  = w1t + (size_t)grB * K + swc;

  f32x4 acc[4][2] = {};

#define G1_STAGE(BUF, KT) do { \
    gl_lds16(a0p + (KT), &Ab[BUF][w * 16][0]); \
    gl_lds16(a1p + (KT), &Ab[BUF][64 + w * 16][0]); \
    gl_lds16(bp  + (KT), &Bb[BUF][w * 16][0]); \
  } while (0)

  G1_STAGE(0, 0);
  G1_STAGE(1, 32);
  asm volatile("s_waitcnt vmcnt(3)" ::: "memory");  // stage 0 done; stage 1 in flight
  __builtin_amdgcn_s_barrier();

  for (int s = 0; s < 16; ++s) {
    const int cur = s & 1;
    short8 af[4], bf[2];
#pragma unroll
    for (int m = 0; m < 4; ++m) af[m] = *(const short8*)&Ab[cur][wr * 64 + m * 16 + lr][rch];
#pragma unroll
    for (int n = 0; n < 2; ++n) bf[n] = *(const short8*)&Bb[cur][wc * 32 + n * 16 + lr][rch];
    if (s < 14) {
      asm volatile("s_waitcnt lgkmcnt(0)" ::: "memory");  // frags in regs
      __builtin_amdgcn_s_barrier();                       // all waves done with buf cur
      G1_STAGE(cur, (s + 2) * 32);                        // tile s+2 -> buf cur
    }
#pragma unroll
    for (int m = 0; m < 4; ++m)
#pragma unroll
      for (int n = 0; n < 2; ++n)
        acc[m][n] = __builtin_amdgcn_mfma_f32_16x16x32_bf16(af[m], bf[n], acc[m][n], 0, 0, 0);
    if (s < 14)      asm volatile("s_waitcnt vmcnt(3)" ::: "memory");  // s+1 landed; s+2 in flight
    else if (s == 14) asm volatile("s_waitcnt vmcnt(0)" ::: "memory"); // last stage (tile 15) landed
    if (s < 15) __builtin_amdgcn_s_barrier();
  }
#undef G1_STAGE

#pragma unroll
  for (int m = 0; m < 4; ++m) {
#pragma unroll
    for (int n = 0; n < 2; ++n) {
      const int col = bcol + wc * 32 + n * 16 + lr;
#pragma unroll
      for (int j = 0; j < 4; ++j) {
        const int row = brow + wr * 64 + m * 16 + lk * 4 + j;
        if (row < M) hs1b[(size_t)row * N + col] = f2b(acc[m][n][j] * dinv[row]);
      }
    }
  }
}

// ---------------- FUSED agg1 + relu/bias + GEMM2 + prescale -> hs2b ----------------
// R2's proven 8-deep gather batch. 16 nodes/block, wave gathers 4 nodes;
// phase 2: wave w computes cols w*16..w*16+15 of the 16x64 output.
__global__ __launch_bounds__(256) void k_agg1g(const int* __restrict__ rowptr,
    const int* __restrict__ csr, const unsigned short* __restrict__ hs1b,
    const float* __restrict__ dinv, const float* __restrict__ b1,
    const unsigned short* __restrict__ w2t, unsigned short* __restrict__ hs2b) {
  const int M = NNODES;
  __shared__ unsigned short h1t[16][264];  // 8.4 KB
  const int tid = threadIdx.x;
  const int w = tid >> 6, lane = tid & 63;
  const int lr = lane & 15, lk = lane >> 4;
  const int brow = blockIdx.x * 16;

  const float4 bb = *(const float4*)(b1 + lane * 4);

  // ---- phase 1: each wave aggregates 4 nodes ----
  for (int i = 0; i < 4; ++i) {
    const int ldsrow = w * 4 + i;
    const int d = brow + ldsrow;
    f32x4 acc = {0.f, 0.f, 0.f, 0.f};
    if (d < M) {
      const int a = rowptr[d], bnd = rowptr[d + 1];
      ushort4 sv = *(const ushort4*)(hs1b + (size_t)d * 256 + lane * 4);  // self loop
      acc[0] = b2f(sv.x); acc[1] = b2f(sv.y); acc[2] = b2f(sv.z); acc[3] = b2f(sv.w);
      int e = a;
      for (; e + 8 <= bnd; e += 8) {
        int s[8];
#pragma unroll
        for (int j = 0; j < 8; ++j) s[j] = csr[e + j];
        ushort4 v[8];
#pragma unroll
        for (int j = 0; j < 8; ++j) v[j] = *(const ushort4*)(hs1b + (size_t)s[j] * 256 + lane * 4);
#pragma unroll
        for (int j = 0; j < 8; ++j) {
          acc[0] += b2f(v[j].x); acc[1] += b2f(v[j].y);
          acc[2] += b2f(v[j].z); acc[3] += b2f(v[j].w);
        }
      }
      for (; e + 2 <= bnd; e += 2) {
        int s0 = csr[e], s1 = csr[e + 1];
        ushort4 v0 = *(const ushort4*)(hs1b + (size_t)s0 * 256 + lane * 4);
        ushort4 v1 = *(const ushort4*)(hs1b + (size_t)s1 * 256 + lane * 4);
        acc[0] += b2f(v0.x) + b2f(v1.x); acc[1] += b2f(v0.y) + b2f(v1.y);
        acc[2] += b2f(v0.z) + b2f(v1.z); acc[3] += b2f(v0.w) + b2f(v1.w);
      }
      for (; e < bnd; ++e) {
        int s0 = csr[e];
        ushort4 v0 = *(const ushort4*)(hs1b + (size_t)s0 * 256 + lane * 4);
        acc[0] += b2f(v0.x); acc[1] += b2f(v0.y); acc[2] += b2f(v0.z); acc[3] += b2f(v0.w);
      }
      const float di = dinv[d];
      acc[0] = fmaxf(0.f, acc[0] * di + bb.x);
      acc[1] = fmaxf(0.f, acc[1] * di + bb.y);
      acc[2] = fmaxf(0.f, acc[2] * di + bb.z);
      acc[3] = fmaxf(0.f, acc[3] * di + bb.w);
    }
    uint2 pk;
    pk.x = pkcvt(acc[0], acc[1]);
    pk.y = pkcvt(acc[2], acc[3]);
    *(uint2*)&h1t[ldsrow][lane * 4] = pk;
  }

  __syncthreads();

  // ---- phase 2: 16x64x256 MFMA; wave w -> cols w*16..w*16+15 ----
  f32x4 acc2 = {};
#pragma unroll
  for (int s = 0; s < 8; ++s) {
    short8 af = *(const short8*)&h1t[lr][s * 32 + lk * 8];
    short8 bfv = *(const short8*)(w2t + (size_t)(w * 16 + lr) * 256 + s * 32 + lk * 8);
    acc2 = __builtin_amdgcn_mfma_f32_16x16x32_bf16(af, bfv, acc2, 0, 0, 0);
  }

  {
    const int col = w * 16 + lr;
#pragma unroll
    for (int j = 0; j < 4; ++j) {
      const int row = brow + lk * 4 + j;
      if (row < M) hs2b[(size_t)row * 64 + col] = f2b(acc2[j] * dinv[row]);
    }
  }
}

// ---------------- fused agg2 + bias + log_softmax: wave per dst, 2 edges/issue ----------------
// Half-wave split: lane = (h, c2); lane loads ushort2 (cols c2*2, c2*2+1) of
// edge base+h+2j -> each gather instruction covers 2 edges (was 1), halving
// per-edge issue count; 8-deep batch keeps 16 edges in flight. Halves combine
// via one shfl_xor(32); after that both halves hold identical values, so the
// 16..1 reductions produce the full-64-col softmax in each half; h==0 stores
// float2.
__global__ __launch_bounds__(256) void k_agg2f(const int* __restrict__ rowptr,
    const int* __restrict__ csr, const unsigned short* __restrict__ hs2b,
    const float* __restrict__ dinv, const float* __restrict__ b2,
    float* __restrict__ out) {
  const int d = blockIdx.x * 4 + (threadIdx.x >> 6);
  if (d >= NNODES) return;
  const int lane = threadIdx.x & 63;
  const int h = lane >> 5;        // which edge of a pair
  const int c2 = lane & 31;       // ushort2 column pair index
  const int a = rowptr[d], bnd = rowptr[d + 1];

  float acc0 = 0.f, acc1 = 0.f;
  {  // self loop, counted once (h==0 half)
    unsigned int sv = *(const unsigned int*)(hs2b + (size_t)d * 64 + c2 * 2);
    if (h == 0) { acc0 = b2f((unsigned short)(sv & 0xffff)); acc1 = b2f((unsigned short)(sv >> 16)); }
  }

  int base = a;
  for (; base + 16 <= bnd; base += 16) {
    int s[8];
#pragma unroll
    for (int j = 0; j < 8; ++j) s[j] = csr[base + h + 2 * j];
    unsigned int v[8];
#pragma unroll
    for (int j = 0; j < 8; ++j) v[j] = *(const unsigned int*)(hs2b + (size_t)s[j] * 64 + c2 * 2);
#pragma unroll
    for (int j = 0; j < 8; ++j) {
      acc0 += b2f((unsigned short)(v[j] & 0xffff));
      acc1 += b2f((unsigned short)(v[j] >> 16));
    }
  }
  for (; base + 2 <= bnd; base += 2) {
    int s0 = csr[base + h];
    unsigned int v = *(const unsigned int*)(hs2b + (size_t)s0 * 64 + c2 * 2);
    acc0 += b2f((unsigned short)(v & 0xffff));
    acc1 += b2f((unsigned short)(v >> 16));
  }
  if (base < bnd && h == 0) {  // odd leftover edge
    int s0 = csr[base];
    unsigned int v = *(const unsigned int*)(hs2b + (size_t)s0 * 64 + c2 * 2);
    acc0 += b2f((unsigned short)(v & 0xffff));
    acc1 += b2f((unsigned short)(v >> 16));
  }

  // combine half-waves: lanes l and l^32 have the same c2
  acc0 += __shfl_xor(acc0, 32, 64);
  acc1 += __shfl_xor(acc1, 32, 64);

  const float di = dinv[d];
  const float2 bv = *(const float2*)(b2 + c2 * 2);
  const float v0 = acc0 * di + bv.x;
  const float v1 = acc1 * di + bv.y;

  float m = fmaxf(v0, v1);
#pragma unroll
  for (int o = 16; o > 0; o >>= 1) m = fmaxf(m, __shfl_xor(m, o, 64));
  float s = expf(v0 - m) + expf(v1 - m);
#pragma unroll
  for (int o = 16; o > 0; o >>= 1) s += __shfl_xor(s, o, 64);
  const float ls = logf(s);
  if (h == 0) {
    float2 r; r.x = v0 - m - ls; r.y = v1 - m - ls;
    *(float2*)(out + (size_t)d * 64 + c2 * 2) = r;
  }
}

extern "C" void kernel_launch(void* const* d_in, const int* in_sizes, int n_in,
                              void* d_out, int out_size, void* d_ws, size_t ws_size,
                              hipStream_t stream) {
  const float* x  = (const float*)d_in[0];
  const int*   ei = (const int*)d_in[1];
  const float* W1 = (const float*)d_in[2];
  const float* b1 = (const float*)d_in[3];
  const float* W2 = (const float*)d_in[4];
  const float* b2 = (const float*)d_in[5];
  float* out = (float*)d_out;
  const int E = in_sizes[1] / 2;
  const int n = NNODES;
  const int nblk = (n + 255) / 256;

  char* ws = (char*)d_ws;
  size_t off = 0;
  auto alloc = [&](size_t bytes) { char* p = ws + off; off = (off + bytes + 255) & ~(size_t)255; return p; };
  int*            deg    = (int*)alloc((size_t)n * 4);
  float*          dinv   = (float*)alloc((size_t)n * 4);
  int*            excl   = (int*)alloc((size_t)n * 4);
  int*            blksum = (int*)alloc((size_t)nblk * 4);
  int*            rowptr = (int*)alloc((size_t)(n + 1) * 4);
  int*            rnk    = (int*)alloc((size_t)E * 4);
  int*            csr    = (int*)alloc((size_t)E * 4);
  unsigned short* w1t    = (unsigned short*)alloc(256 * 512 * 2);
  unsigned short* w2t    = (unsigned short*)alloc(64 * 256 * 2);
  unsigned short* hs1b   = (unsigned short*)alloc((size_t)n * 256 * 2);
  unsigned short* hs2b   = (unsigned short*)alloc((size_t)n * 64 * 2);
  unsigned short* xb     = (unsigned short*)alloc((size_t)n * 512 * 2);  // bf16 copy of x
  (void)ws_size; (void)n_in; (void)out_size;

  hipMemsetAsync(deg, 0, (size_t)n * 4, stream);
  k_deg<<<(E + 255) / 256, 256, 0, stream>>>(ei, deg, E, rnk, W1, W2, w1t, w2t);
  k_scanA<<<nblk, 256, 0, stream>>>(deg, excl, blksum, dinv, n);
  k_scanC<<<nblk, 256, 0, stream>>>(excl, blksum, rowptr, n, E);
  // atomic-free fill (rank trick) + xb conversion fused
  k_fillx<<<(NNODES * 512 / 8 + 255) / 256, 256, 0, stream>>>(ei, rowptr, rnk, csr, E, x, xb);
  // 49 groups x 32 blocks: row = (bid>>5)*8 + (bid&7), col = (bid>>3)&3
  k_gemm1<<<49 * 32, 256, 0, stream>>>(xb, w1t, dinv, hs1b);
  k_agg1g<<<(n + 15) / 16, 256, 0, stream>>>(rowptr, csr, hs1b, dinv, b1, w2t, hs2b);
  k_agg2f<<<(n + 3) / 4, 256, 0, stream>>>(rowptr, csr, hs2b, dinv, b2, out);
}

// Round 10
// 220.610 us; speedup vs baseline: 1.0186x; 1.0083x over previous
//
#include <hip/hip_runtime.h>
#include <hip/hip_bf16.h>

typedef __attribute__((ext_vector_type(8))) short short8;
typedef __attribute__((ext_vector_type(4))) float f32x4;

#define NNODES 50000

__device__ __forceinline__ float b2f(unsigned short s) {
  union { unsigned int u; float f; } c; c.u = ((unsigned int)s) << 16;
  return c.f;
}
__device__ __forceinline__ unsigned short f2b(float f) {
  return __bfloat16_as_ushort(__float2bfloat16(f));  // RNE
}
__device__ __forceinline__ unsigned int pkcvt(float a, float b) {
  return (unsigned int)f2b(a) | ((unsigned int)f2b(b) << 16);
}

// global_load_lds, 16B per lane: per-lane GLOBAL src addr, wave-uniform LDS
// base; HW writes LDS at base + lane*16 (m104 semantics).
__device__ __forceinline__ void gl_lds16(const void* g, void* l) {
  __builtin_amdgcn_global_load_lds((const __attribute__((address_space(1))) unsigned int*)g,
                                   (__attribute__((address_space(3))) unsigned int*)l, 16, 0, 0);
}

// ---------------- degree histogram (+rank capture) + W transpose/bf16 ----------------
__global__ __launch_bounds__(256) void k_deg(const int* __restrict__ ei, int* __restrict__ deg, int E,
                                             int* __restrict__ rnk,
                                             const float* __restrict__ W1, const float* __restrict__ W2,
                                             unsigned short* __restrict__ w1t, unsigned short* __restrict__ w2t) {
  int idx = blockIdx.x * 256 + threadIdx.x;
  if (idx < E) {
    int r = atomicAdd(&deg[ei[E + idx]], 1);
    rnk[idx] = r;
  }
  if (idx < 256 * 512) { int nn = idx >> 9, kk = idx & 511; w1t[idx] = f2b(W1[kk * 256 + nn]); }
  int i2 = idx - 256 * 512;
  if (i2 >= 0 && i2 < 64 * 256) { int nn = i2 >> 8, kk = i2 & 255; w2t[i2] = f2b(W2[kk * 64 + nn]); }
}

// ---------------- scan phase A ----------------
__global__ __launch_bounds__(256) void k_scanA(const int* __restrict__ deg, int* __restrict__ excl,
                                               int* __restrict__ blksum, float* __restrict__ dinv, int n) {
  const int i = blockIdx.x * 256 + threadIdx.x;
  const int lane = threadIdx.x & 63, wid = threadIdx.x >> 6;
  const int v = (i < n) ? deg[i] : 0;
  int x = v;
#pragma unroll
  for (int o = 1; o < 64; o <<= 1) {
    int y = __shfl_up(x, o, 64);
    if (lane >= o) x += y;
  }
  __shared__ int wsum[4];
  if (lane == 63) wsum[wid] = x;
  __syncthreads();
  int woff = 0;
  for (int w = 0; w < wid; ++w) woff += wsum[w];
  const int incl = x + woff;
  if (i < n) {
    excl[i] = incl - v;
    dinv[i] = rsqrtf((float)v + 1.0f);  // +1 self loop
  }
  if (threadIdx.x == 255) blksum[blockIdx.x] = incl;
}

// ---------------- scan phase C ----------------
__global__ __launch_bounds__(256) void k_scanC(const int* __restrict__ excl, const int* __restrict__ blksum,
                                               int* __restrict__ rowptr, int n, int E) {
  const int t = threadIdx.x;
  int partial = 0;
  for (int j = t; j < (int)blockIdx.x; j += 256) partial += blksum[j];
#pragma unroll
  for (int o = 32; o > 0; o >>= 1) partial += __shfl_xor(partial, o, 64);
  __shared__ int ws[4];
  if ((t & 63) == 0) ws[t >> 6] = partial;
  __syncthreads();
  const int off = ws[0] + ws[1] + ws[2] + ws[3];
  const int i = blockIdx.x * 256 + t;
  if (i < n) rowptr[i] = excl[i] + off;
  if (i == 0) rowptr[n] = E;
}

// ---------------- atomic-free CSR fill + x->bf16 conversion (fused) ----------------
__global__ __launch_bounds__(256) void k_fillx(const int* __restrict__ ei, const int* __restrict__ rowptr,
                                               const int* __restrict__ rnk, int* __restrict__ csr, int E,
                                               const float* __restrict__ x, unsigned short* __restrict__ xb) {
  int idx = blockIdx.x * 256 + threadIdx.x;
  if (idx < E) {
    const int dst = ei[E + idx];
    csr[rowptr[dst] + rnk[idx]] = ei[idx];
  }
  if (idx < (NNODES * 512) / 8) {
    const float4 v0 = *(const float4*)(x + (size_t)idx * 8);
    const float4 v1 = *(const float4*)(x + (size_t)idx * 8 + 4);
    uint4 p;
    p.x = pkcvt(v0.x, v0.y); p.y = pkcvt(v0.z, v0.w);
    p.z = pkcvt(v1.x, v1.y); p.w = pkcvt(v1.z, v1.w);
    *(uint4*)(xb + (size_t)idx * 8) = p;
  }
}

// ---------------- GEMM1: hs1h = bf16(dinv[row] * (xb @ W1)), HALF-blocked ----------------
// R7 config (128x64, measured local optimum). Depth-2 pipelined gl_lds
// staging, counted vmcnt(3), both-sides chunk-XOR swizzle. Output layout
// hs1h[half][node][128] (half = col>>7): each 128-col half-table is a
// contiguous 12.8MB slab so k_agg1's half-passes fetch only 256B per touched
// row per XCD (R2's full-row layout forced 512B -> 185MB replication fetch).
__global__ __launch_bounds__(256) void k_gemm1(const unsigned short* __restrict__ xb,
    const unsigned short* __restrict__ w1t, const float* __restrict__ dinv,
    unsigned short* __restrict__ hs1h) {
  const int M = NNODES, K = 512;
  const int NRB = (NNODES + 127) / 128;  // 391
  const int bid = blockIdx.x;
  const int rowblk = (bid >> 5) * 8 + (bid & 7);
  const int colblk = (bid >> 3) & 3;
  if (rowblk >= NRB) return;

  __shared__ unsigned short Ab[2][128][32];  // 16 KB
  __shared__ unsigned short Bb[2][64][32];   //  8 KB

  const int tid = threadIdx.x;
  const int w = tid >> 6, lane = tid & 63;
  const int sub = lane >> 2;                 // staging row within wave window
  const int brow = rowblk * 128, bcol = colblk * 64;
  const int wr = w >> 1, wc = w & 1;         // 2x2 wave grid, 64x32 out each
  const int lr = lane & 15, lk = lane >> 4;

  const int swc = ((lane & 3) ^ ((lane >> 3) & 3)) * 8;   // pre-swizzled src chunk
  const int rch = (lk ^ ((lr >> 1) & 3)) * 8;             // read-side swizzled chunk

  int gr0 = brow + w * 16 + sub;      if (gr0 >= M) gr0 = M - 1;
  int gr1 = brow + 64 + w * 16 + sub; if (gr1 >= M) gr1 = M - 1;
  const int grB = bcol + w * 16 + sub;

  const unsigned short* a0p = xb + (size_t)gr0 * K + swc;
  const unsigned short* a1p = xb + (size_t)gr1 * K + swc;
  const unsigned short* bp  = w1t + (size_t)grB * K + swc;

  f32x4 acc[4][2] = {};

#define G1_STAGE(BUF, KT) do { \
    gl_lds16(a0p + (KT), &Ab[BUF][w * 16][0]); \
    gl_lds16(a1p + (KT), &Ab[BUF][64 + w * 16][0]); \
    gl_lds16(bp  + (KT), &Bb[BUF][w * 16][0]); \
  } while (0)

  G1_STAGE(0, 0);
  G1_STAGE(1, 32);
  asm volatile("s_waitcnt vmcnt(3)" ::: "memory");  // stage 0 done; stage 1 in flight
  __builtin_amdgcn_s_barrier();

  for (int s = 0; s < 16; ++s) {
    const int cur = s & 1;
    short8 af[4], bf[2];
#pragma unroll
    for (int m = 0; m < 4; ++m) af[m] = *(const short8*)&Ab[cur][wr * 64 + m * 16 + lr][rch];
#pragma unroll
    for (int n = 0; n < 2; ++n) bf[n] = *(const short8*)&Bb[cur][wc * 32 + n * 16 + lr][rch];
    if (s < 14) {
      asm volatile("s_waitcnt lgkmcnt(0)" ::: "memory");  // frags in regs
      __builtin_amdgcn_s_barrier();                       // all waves done with buf cur
      G1_STAGE(cur, (s + 2) * 32);                        // tile s+2 -> buf cur
    }
#pragma unroll
    for (int m = 0; m < 4; ++m)
#pragma unroll
      for (int n = 0; n < 2; ++n)
        acc[m][n] = __builtin_amdgcn_mfma_f32_16x16x32_bf16(af[m], bf[n], acc[m][n], 0, 0, 0);
    if (s < 14)      asm volatile("s_waitcnt vmcnt(3)" ::: "memory");  // s+1 landed; s+2 in flight
    else if (s == 14) asm volatile("s_waitcnt vmcnt(0)" ::: "memory"); // last stage (tile 15) landed
    if (s < 15) __builtin_amdgcn_s_barrier();
  }
#undef G1_STAGE

#pragma unroll
  for (int m = 0; m < 4; ++m) {
#pragma unroll
    for (int n = 0; n < 2; ++n) {
      const int col = bcol + wc * 32 + n * 16 + lr;          // 0..255
      unsigned short* dsth = hs1h + (size_t)(col >> 7) * ((size_t)NNODES * 128);
      const int cw = col & 127;
#pragma unroll
      for (int j = 0; j < 4; ++j) {
        const int row = brow + wr * 64 + m * 16 + lk * 4 + j;
        if (row < M) dsth[(size_t)row * 128 + cw] = f2b(acc[m][n][j] * dinv[row]);
      }
    }
  }
}

// ---------------- agg1: 2-pass half-row gather + relu/bias -> h1agg [2][n][128] ----------------
// half = bid&1 -> via round-robin dispatch, XCD parity is fixed per half, so
// each XCD gathers only ONE 12.8MB half-table: per-XCD fetch = touched-rows x
// 256B (R2's fused full-row version fetched 512B/row -> 185MB; predicted here
// ~90-110MB). Per-edge issue count is IDENTICAL to R2 (one 4B/lane load per
// edge per wave); total instructions only 2x (R2 was 29% VALU-busy). No LDS,
// low VGPR -> 8 blocks/CU of independent gather streams. Wave w owns dst
// chunk*4+w; 8-deep gather batch (R2's proven depth).
__global__ __launch_bounds__(256) void k_agg1(const int* __restrict__ rowptr,
    const int* __restrict__ csr, const unsigned short* __restrict__ hs1h,
    const float* __restrict__ dinv, const float* __restrict__ b1,
    unsigned short* __restrict__ h1agg) {
  const int half = blockIdx.x & 1;
  const int chunk = blockIdx.x >> 1;
  const int w = threadIdx.x >> 6, lane = threadIdx.x & 63;
  const int d = chunk * 4 + w;
  if (d >= NNODES) return;
  const unsigned short* __restrict__ src = hs1h + (size_t)half * ((size_t)NNODES * 128);
  const int a = rowptr[d], bnd = rowptr[d + 1];

  // self loop
  unsigned int sv = *(const unsigned int*)(src + (size_t)d * 128 + lane * 2);
  float a0 = b2f((unsigned short)(sv & 0xffff));
  float a1 = b2f((unsigned short)(sv >> 16));

  int e = a;
  for (; e + 8 <= bnd; e += 8) {
    int s[8];
#pragma unroll
    for (int j = 0; j < 8; ++j) s[j] = csr[e + j];
    unsigned int v[8];
#pragma unroll
    for (int j = 0; j < 8; ++j) v[j] = *(const unsigned int*)(src + (size_t)s[j] * 128 + lane * 2);
#pragma unroll
    for (int j = 0; j < 8; ++j) {
      a0 += b2f((unsigned short)(v[j] & 0xffff));
      a1 += b2f((unsigned short)(v[j] >> 16));
    }
  }
  for (; e + 2 <= bnd; e += 2) {
    int s0 = csr[e], s1 = csr[e + 1];
    unsigned int v0 = *(const unsigned int*)(src + (size_t)s0 * 128 + lane * 2);
    unsigned int v1 = *(const unsigned int*)(src + (size_t)s1 * 128 + lane * 2);
    a0 += b2f((unsigned short)(v0 & 0xffff)) + b2f((unsigned short)(v1 & 0xffff));
    a1 += b2f((unsigned short)(v0 >> 16)) + b2f((unsigned short)(v1 >> 16));
  }
  for (; e < bnd; ++e) {
    int s0 = csr[e];
    unsigned int v0 = *(const unsigned int*)(src + (size_t)s0 * 128 + lane * 2);
    a0 += b2f((unsigned short)(v0 & 0xffff));
    a1 += b2f((unsigned short)(v0 >> 16));
  }

  const float di = dinv[d];
  const float2 bb = *(const float2*)(b1 + half * 128 + lane * 2);
  a0 = fmaxf(0.f, a0 * di + bb.x);
  a1 = fmaxf(0.f, a1 * di + bb.y);
  *(unsigned int*)(h1agg + (size_t)half * ((size_t)NNODES * 128) + (size_t)d * 128 + lane * 2) =
      pkcvt(a0, a1);
}

// ---------------- GEMM2: hs2b = bf16(dinv[row] * (h1agg @ W2)) ----------------
// M=50000, N=64, K=256. A is half-blocked h1agg[2][n][128]: k-step s reads
// cols (s&3)*32 of half s>>2 -- a contiguous 64B run per row. Tile 64x64,
// 4 waves 2x2 (32x32 out each), BK=32, 8 k-steps, depth-2 pipelined gl_lds
// with counted vmcnt(2), same chunk-XOR swizzle as gemm1. 782 blocks.
__global__ __launch_bounds__(256) void k_gemm2(const unsigned short* __restrict__ h1agg,
    const unsigned short* __restrict__ w2t, const float* __restrict__ dinv,
    unsigned short* __restrict__ hs2b) {
  const int M = NNODES;
  const size_t HL = (size_t)NNODES * 128;
  const int brow = blockIdx.x * 64;

  __shared__ unsigned short As[2][64][32];  // 4 KB x2
  __shared__ unsigned short Bs[2][64][32];  // 4 KB x2

  const int tid = threadIdx.x;
  const int w = tid >> 6, lane = tid & 63;
  const int sub = lane >> 2;
  const int wr = w >> 1, wc = w & 1;
  const int lr = lane & 15, lk = lane >> 4;

  const int swc = ((lane & 3) ^ ((lane >> 3) & 3)) * 8;   // pre-swizzled src chunk
  const int rch = (lk ^ ((lr >> 1) & 3)) * 8;             // read-side swizzled chunk

  int gr = brow + w * 16 + sub; if (gr >= M) gr = M - 1;
  const unsigned short* ap = h1agg + (size_t)gr * 128 + swc;            // + (s>>2)*HL + (s&3)*32
  const unsigned short* bp = w2t + (size_t)(w * 16 + sub) * 256 + swc;  // + s*32

  f32x4 acc[2][2] = {};

#define G2_STAGE(BUF, S) do { \
    gl_lds16(ap + (size_t)((S) >> 2) * HL + ((S) & 3) * 32, &As[BUF][w * 16][0]); \
    gl_lds16(bp + (S) * 32,                                  &Bs[BUF][w * 16][0]); \
  } while (0)

  G2_STAGE(0, 0);
  G2_STAGE(1, 1);
  asm volatile("s_waitcnt vmcnt(2)" ::: "memory");  // stage 0 done; stage 1 in flight
  __builtin_amdgcn_s_barrier();

  for (int s = 0; s < 8; ++s) {
    const int cur = s & 1;
    short8 af[2], bf[2];
#pragma unroll
    for (int m = 0; m < 2; ++m) af[m] = *(const short8*)&As[cur][wr * 32 + m * 16 + lr][rch];
#pragma unroll
    for (int n = 0; n < 2; ++n) bf[n] = *(const short8*)&Bs[cur][wc * 32 + n * 16 + lr][rch];
    if (s < 6) {
      asm volatile("s_waitcnt lgkmcnt(0)" ::: "memory");
      __builtin_amdgcn_s_barrier();
      G2_STAGE(cur, s + 2);
    }
#pragma unroll
    for (int m = 0; m < 2; ++m)
#pragma unroll
      for (int n = 0; n < 2; ++n)
        acc[m][n] = __builtin_amdgcn_mfma_f32_16x16x32_bf16(af[m], bf[n], acc[m][n], 0, 0, 0);
    if (s < 6)      asm volatile("s_waitcnt vmcnt(2)" ::: "memory");
    else if (s == 6) asm volatile("s_waitcnt vmcnt(0)" ::: "memory");
    if (s < 7) __builtin_amdgcn_s_barrier();
  }
#undef G2_STAGE

#pragma unroll
  for (int m = 0; m < 2; ++m) {
#pragma unroll
    for (int n = 0; n < 2; ++n) {
      const int col = wc * 32 + n * 16 + lr;
#pragma unroll
      for (int j = 0; j < 4; ++j) {
        const int row = brow + wr * 32 + m * 16 + lk * 4 + j;
        if (row < M) hs2b[(size_t)row * 64 + col] = f2b(acc[m][n][j] * dinv[row]);
      }
    }
  }
}

// ---------------- fused agg2 + bias + log_softmax: wave per dst node (R7 version) ----------------
__global__ __launch_bounds__(256) void k_agg2f(const int* __restrict__ rowptr,
    const int* __restrict__ csr, const unsigned short* __restrict__ hs2b,
    const float* __restrict__ dinv, const float* __restrict__ b2,
    float* __restrict__ out) {
  const int d = blockIdx.x * 4 + (threadIdx.x >> 6);
  if (d >= NNODES) return;
  const int lane = threadIdx.x & 63;
  const int a = rowptr[d], bnd = rowptr[d + 1];

  float acc = b2f(hs2b[(size_t)d * 64 + lane]);

  int i = a;
  for (; i + 16 <= bnd; i += 16) {
    int s[16];
#pragma unroll
    for (int j = 0; j < 16; ++j) s[j] = csr[i + j];
    unsigned short v[16];
#pragma unroll
    for (int j = 0; j < 16; ++j) v[j] = hs2b[(size_t)s[j] * 64 + lane];
#pragma unroll
    for (int j = 0; j < 16; ++j) acc += b2f(v[j]);
  }
  for (; i + 4 <= bnd; i += 4) {
    int s[4];
#pragma unroll
    for (int j = 0; j < 4; ++j) s[j] = csr[i + j];
    unsigned short v[4];
#pragma unroll
    for (int j = 0; j < 4; ++j) v[j] = hs2b[(size_t)s[j] * 64 + lane];
#pragma unroll
    for (int j = 0; j < 4; ++j) acc += b2f(v[j]);
  }
  for (; i < bnd; ++i) acc += b2f(hs2b[(size_t)csr[i] * 64 + lane]);

  float v = acc * dinv[d] + b2[lane];
  float m = v;
#pragma unroll
  for (int o = 32; o > 0; o >>= 1) m = fmaxf(m, __shfl_xor(m, o, 64));
  float ex = expf(v - m);
  float s = ex;
#pragma unroll
  for (int o = 32; o > 0; o >>= 1) s += __shfl_xor(s, o, 64);
  out[(size_t)d * 64 + lane] = v - m - logf(s);
}

extern "C" void kernel_launch(void* const* d_in, const int* in_sizes, int n_in,
                              void* d_out, int out_size, void* d_ws, size_t ws_size,
                              hipStream_t stream) {
  const float* x  = (const float*)d_in[0];
  const int*   ei = (const int*)d_in[1];
  const float* W1 = (const float*)d_in[2];
  const float* b1 = (const float*)d_in[3];
  const float* W2 = (const float*)d_in[4];
  const float* b2 = (const float*)d_in[5];
  float* out = (float*)d_out;
  const int E = in_sizes[1] / 2;
  const int n = NNODES;
  const int nblk = (n + 255) / 256;

  char* ws = (char*)d_ws;
  size_t off = 0;
  auto alloc = [&](size_t bytes) { char* p = ws + off; off = (off + bytes + 255) & ~(size_t)255; return p; };
  int*            deg    = (int*)alloc((size_t)n * 4);
  float*          dinv   = (float*)alloc((size_t)n * 4);
  int*            excl   = (int*)alloc((size_t)n * 4);
  int*            blksum = (int*)alloc((size_t)nblk * 4);
  int*            rowptr = (int*)alloc((size_t)(n + 1) * 4);
  int*            rnk    = (int*)alloc((size_t)E * 4);
  int*            csr    = (int*)alloc((size_t)E * 4);
  unsigned short* w1t    = (unsigned short*)alloc(256 * 512 * 2);
  unsigned short* w2t    = (unsigned short*)alloc(64 * 256 * 2);
  unsigned short* hs1h   = (unsigned short*)alloc((size_t)n * 256 * 2);  // [2][n][128]
  unsigned short* h1agg  = (unsigned short*)alloc((size_t)n * 256 * 2);  // [2][n][128]
  unsigned short* hs2b   = (unsigned short*)alloc((size_t)n * 64 * 2);
  unsigned short* xb     = (unsigned short*)alloc((size_t)n * 512 * 2);  // bf16 copy of x
  (void)ws_size; (void)n_in; (void)out_size;

  hipMemsetAsync(deg, 0, (size_t)n * 4, stream);
  k_deg<<<(E + 255) / 256, 256, 0, stream>>>(ei, deg, E, rnk, W1, W2, w1t, w2t);
  k_scanA<<<nblk, 256, 0, stream>>>(deg, excl, blksum, dinv, n);
  k_scanC<<<nblk, 256, 0, stream>>>(excl, blksum, rowptr, n, E);
  // atomic-free fill (rank trick) + xb conversion fused
  k_fillx<<<(NNODES * 512 / 8 + 255) / 256, 256, 0, stream>>>(ei, rowptr, rnk, csr, E, x, xb);
  // 49 groups x 32 blocks: row = (bid>>5)*8 + (bid&7), col = (bid>>3)&3
  k_gemm1<<<49 * 32, 256, 0, stream>>>(xb, w1t, dinv, hs1h);
  // 2 half-passes x 12500 dst-chunks; half = bid&1 -> XCD parity fixed
  k_agg1<<<12500 * 2, 256, 0, stream>>>(rowptr, csr, hs1h, dinv, b1, h1agg);
  k_gemm2<<<(n + 63) / 64, 256, 0, stream>>>(h1agg, w2t, dinv, hs2b);
  k_agg2f<<<(n + 3) / 4, 256, 0, stream>>>(rowptr, csr, hs2b, dinv, b2, out);
}